// Round 13
// baseline (434.519 us; speedup 1.0000x reference)
//
#include <hip/hip_runtime.h>
#include <cstdint>
#include <cstddef>

typedef unsigned short u16;
typedef short short8 __attribute__((ext_vector_type(8)));
typedef unsigned short u16x8 __attribute__((ext_vector_type(8)));
typedef unsigned short u16x4 __attribute__((ext_vector_type(4)));
typedef float f32x4 __attribute__((ext_vector_type(4)));

#define DEVI __device__ __forceinline__

#if defined(__has_builtin)
#if __has_builtin(__builtin_amdgcn_global_load_lds)
#define USE_GLD 1
#endif
#endif

DEVI float bf2f(u16 u) { return __uint_as_float(((unsigned)u) << 16); }
DEVI u16 f2bf(float f) {
  unsigned u = __float_as_uint(f);
  u += 0x7FFFu + ((u >> 16) & 1u);  // RNE
  return (u16)(u >> 16);
}

DEVI void stage16(const u16* __restrict__ g, u16* lds_base, int lane) {
#ifdef USE_GLD
  __builtin_amdgcn_global_load_lds(
      (const __attribute__((address_space(1))) unsigned int*)g,
      (__attribute__((address_space(3))) unsigned int*)lds_base, 16, 0, 0);
#else
  *(u16x8*)(lds_base + lane * 8) = *(const u16x8*)g;
#endif
}

// ---------------- CSR build ----------------
__global__ void build_deg(const int* __restrict__ dst, int* __restrict__ deg, int E) {
  int e = blockIdx.x * 256 + threadIdx.x;
  if (e < E) atomicAdd(&deg[dst[e]], 1);
}

__global__ __launch_bounds__(256) void scan1(const int* __restrict__ deg,
                                             int* __restrict__ pref,
                                             int* __restrict__ bsum, int Nn) {
  __shared__ int wsum[4];
  int i = blockIdx.x * 256 + threadIdx.x;
  int lane = threadIdx.x & 63, w = threadIdx.x >> 6;
  int v = (i < Nn) ? deg[i] : 0;
  int s = v;
  for (int off = 1; off < 64; off <<= 1) {
    int t = __shfl_up(s, off, 64);
    if (lane >= off) s += t;
  }
  if (lane == 63) wsum[w] = s;
  __syncthreads();
  int add = 0;
  for (int k = 0; k < w; ++k) add += wsum[k];
  int incl = s + add;
  if (i < Nn) pref[i] = incl - v;
  if (threadIdx.x == 255) bsum[blockIdx.x] = incl;
}

__global__ __launch_bounds__(256) void scan2(int* __restrict__ bsum,
                                             int* __restrict__ row_ofs,
                                             int nb, int Nn) {
  __shared__ int wsum[4];
  int t = threadIdx.x;
  int lane = t & 63, w = t >> 6;
  int v = (t < nb) ? bsum[t] : 0;
  int s = v;
  for (int off = 1; off < 64; off <<= 1) {
    int u = __shfl_up(s, off, 64);
    if (lane >= off) s += u;
  }
  if (lane == 63) wsum[w] = s;
  __syncthreads();
  int add = 0;
  for (int k = 0; k < w; ++k) add += wsum[k];
  int incl = s + add;
  if (t < nb) bsum[t] = incl - v;
  if (t == 255) row_ofs[Nn] = incl;
}

__global__ __launch_bounds__(256) void scan3(const int* __restrict__ pref,
                                             const int* __restrict__ bsum,
                                             int* __restrict__ row_ofs,
                                             int* __restrict__ cursor, int Nn) {
  int i = blockIdx.x * 256 + threadIdx.x;
  if (i < Nn) {
    int r = pref[i] + bsum[blockIdx.x];
    row_ofs[i] = r;
    cursor[i] = r;
  }
}

__global__ void csr_fill(const int* __restrict__ src, const int* __restrict__ dst,
                         int* __restrict__ cursor, int* __restrict__ col, int E) {
  int e = blockIdx.x * 256 + threadIdx.x;
  if (e < E) {
    int p = atomicAdd(&cursor[dst[e]], 1);
    col[p] = src[e];
  }
}

// ------------- merged weight pack -------------
__global__ __launch_bounds__(256) void pack_all(
    const float* __restrict__ W1, const float* __restrict__ W2,
    const float* __restrict__ Wh1, u16* __restrict__ B1t,
    u16* __restrict__ B2t, u16* __restrict__ Bht) {
  int b = blockIdx.x;
  if (b < 1024) {
    int c = b >> 1;
    int k = (b & 1) * 256 + threadIdx.x;
    if (k < 384) {
      float v = (c < 256) ? W1[(size_t)k * 256 + c]
                          : W1[(size_t)(384 + k) * 256 + (c - 256)];
      B1t[(size_t)c * 384 + k] = f2bf(v);
    }
  } else if (b < 1536) {
    int c = b - 1024;
    int k = threadIdx.x;
    float v = (c < 256) ? W2[(size_t)k * 256 + c]
                        : W2[(size_t)(256 + k) * 256 + (c - 256)];
    B2t[(size_t)c * 256 + k] = f2bf(v);
  } else {
    int c = b - 1536;
    int k = threadIdx.x;
    Bht[(size_t)c * 256 + k] = f2bf(Wh1[(size_t)k * 128 + c]);
  }
}

// ------------- merged bias -------------
__global__ __launch_bounds__(384) void bias_all(
    const float* __restrict__ W1, const float* __restrict__ b1,
    const float* __restrict__ W2, const float* __restrict__ b2,
    const float* __restrict__ Wh1, const float* __restrict__ bh1,
    const float* __restrict__ q, float* __restrict__ cq1,
    float* __restrict__ cq2, float* __restrict__ cqh) {
  __shared__ float part[6];
  int b = blockIdx.x;
  const float* W; const float* bb; float* o; int ld, roff, c;
  if (b < 256)      { W = W1;  bb = b1;  o = cq1; ld = 256; roff = 768; c = b; }
  else if (b < 512) { W = W2;  bb = b2;  o = cq2; ld = 256; roff = 512; c = b - 256; }
  else              { W = Wh1; bb = bh1; o = cqh; ld = 128; roff = 256; c = b - 512; }
  int t = threadIdx.x;
  float p = q[t] * W[(size_t)(roff + t) * ld + c];
  for (int off = 32; off > 0; off >>= 1) p += __shfl_down(p, off, 64);
  if ((t & 63) == 0) part[t >> 6] = p;
  __syncthreads();
  if (t == 0) {
    float acc = bb[c];
    for (int w = 0; w < 6; ++w) acc += part[w];
    o[c] = acc;
  }
}

// ========== direct-fragment GEMM: NO LDS/barriers in K-loop ==========
// Fragments loaded straight from global: B 16-rows x 64B lines, L2-resident
// (<=393KB). A rows read once. LDS only in epilogue (full-line C stores).
#define W_NC 512
#define ES 520

#define GEMM_DIR_EPILOGUE()                                                    \
  {                                                                            \
    _Pragma("unroll") for (int mt = 0; mt < 4; ++mt) {                         \
      __syncthreads();                                                         \
      _Pragma("unroll") for (int nt = 0; nt < 8; ++nt) {                       \
        int col = wave * 128 + nt * 16 + m;                                    \
        float bb = (col < bias_len) ? bias[col] : 0.0f;                        \
        _Pragma("unroll") for (int r = 0; r < 4; ++r) {                        \
          float v = acc[mt][nt][r] + bb;                                       \
          if (relu) v = fmaxf(v, 0.0f);                                        \
          eplds[(quad * 4 + r) * ES + col] = f2bf(v);                          \
        }                                                                      \
      }                                                                        \
      __syncthreads();                                                         \
      _Pragma("unroll") for (int p = 0; p < 4; ++p) {                          \
        int row_loc = p * 4 + wave;                                            \
        int grow = row0 + mt * 16 + row_loc;                                   \
        if (grow < M)                                                          \
          *(u16x8*)&C[(size_t)grow * W_NC + lane * 8] =                        \
              *(const u16x8*)&eplds[row_loc * ES + lane * 8];                  \
      }                                                                        \
    }                                                                          \
  }

__global__ __launch_bounds__(256, 2) void gemm_dir_f32a(
    const float* __restrict__ A, const u16* __restrict__ Bt,
    u16* __restrict__ C, const float* __restrict__ bias,
    int M, int K, int bias_len, int relu) {
  __shared__ __align__(16) u16 eplds[16 * ES];  // epilogue only (16.6 KB)

  const int tid = threadIdx.x;
  const int lane = tid & 63;
  const int wave = tid >> 6;
  const int row0 = blockIdx.x * 64;
  const int m = lane & 15;
  const int quad = lane >> 4;

  const float* pa[4];
#pragma unroll
  for (int mt = 0; mt < 4; ++mt) {
    int r = row0 + mt * 16 + m;
    if (r >= M) r = M - 1;
    pa[mt] = A + (size_t)r * K + quad * 8;
  }
  const u16* pb[8];
#pragma unroll
  for (int nt = 0; nt < 8; ++nt)
    pb[nt] = Bt + (size_t)(wave * 128 + nt * 16 + m) * K + quad * 8;

  f32x4 acc[4][8] = {};

#pragma unroll 2
  for (int k0 = 0; k0 < K; k0 += 32) {
    short8 bf[8];
#pragma unroll
    for (int nt = 0; nt < 8; ++nt)
      bf[nt] = *(const short8*)(pb[nt] + k0);
    short8 af[4];
#pragma unroll
    for (int mt = 0; mt < 4; ++mt) {
      f32x4 a0 = *(const f32x4*)(pa[mt] + k0);
      f32x4 a1 = *(const f32x4*)(pa[mt] + k0 + 4);
      u16x8 h;
#pragma unroll
      for (int j = 0; j < 4; ++j) { h[j] = f2bf(a0[j]); h[j + 4] = f2bf(a1[j]); }
      af[mt] = *(short8*)&h;
    }
#pragma unroll
    for (int mt = 0; mt < 4; ++mt)
#pragma unroll
      for (int nt = 0; nt < 8; ++nt)
        acc[mt][nt] = __builtin_amdgcn_mfma_f32_16x16x32_bf16(
            af[mt], bf[nt], acc[mt][nt], 0, 0, 0);
  }

  GEMM_DIR_EPILOGUE()
}

__global__ __launch_bounds__(256, 2) void gemm_dir_bf16a(
    const u16* __restrict__ A, const u16* __restrict__ Bt,
    u16* __restrict__ C, const float* __restrict__ bias,
    int M, int K, int bias_len, int relu) {
  __shared__ __align__(16) u16 eplds[16 * ES];

  const int tid = threadIdx.x;
  const int lane = tid & 63;
  const int wave = tid >> 6;
  const int row0 = blockIdx.x * 64;
  const int m = lane & 15;
  const int quad = lane >> 4;

  const u16* pa[4];
#pragma unroll
  for (int mt = 0; mt < 4; ++mt) {
    int r = row0 + mt * 16 + m;
    if (r >= M) r = M - 1;
    pa[mt] = A + (size_t)r * K + quad * 8;
  }
  const u16* pb[8];
#pragma unroll
  for (int nt = 0; nt < 8; ++nt)
    pb[nt] = Bt + (size_t)(wave * 128 + nt * 16 + m) * K + quad * 8;

  f32x4 acc[4][8] = {};

#pragma unroll 2
  for (int k0 = 0; k0 < K; k0 += 32) {
    short8 bf[8];
#pragma unroll
    for (int nt = 0; nt < 8; ++nt)
      bf[nt] = *(const short8*)(pb[nt] + k0);
    short8 af[4];
#pragma unroll
    for (int mt = 0; mt < 4; ++mt)
      af[mt] = *(const short8*)(pa[mt] + k0);
#pragma unroll
    for (int mt = 0; mt < 4; ++mt)
#pragma unroll
      for (int nt = 0; nt < 8; ++nt)
        acc[mt][nt] = __builtin_amdgcn_mfma_f32_16x16x32_bf16(
            af[mt], bf[nt], acc[mt][nt], 0, 0, 0);
  }

  GEMM_DIR_EPILOGUE()
}

// ========== fused head: out = relu(h2 @ Wh1h + cqh) . Wh2 + bh2 ==========
// direct-fragment style: 128 rows/block, 128 cols, 2 waves x 64 cols... keep
// proven round-12 structure (works, ~small share of runtime).
#define BM 128
#define BK 32

__global__ __launch_bounds__(256) void gemm_head(
    const u16* __restrict__ A, const u16* __restrict__ Bt,
    const float* __restrict__ cqh, const float* __restrict__ Wh2,
    const float* __restrict__ bh2, float* __restrict__ out, int M, int K) {
  __shared__ float red[128][2];

  const int tid = threadIdx.x;
  const int lane = tid & 63;
  const int wave = tid >> 6;
  const int wm = wave & 1, wn = wave >> 1;
  const int row0 = blockIdx.x * BM;
  const int m = lane & 15;
  const int quad = lane >> 4;

  const u16* pa[4];
#pragma unroll
  for (int mt = 0; mt < 4; ++mt) {
    int r = row0 + wm * 64 + mt * 16 + m;
    if (r >= M) r = M - 1;
    pa[mt] = A + (size_t)r * K + quad * 8;
  }
  const u16* pb[4];
#pragma unroll
  for (int nt = 0; nt < 4; ++nt)
    pb[nt] = Bt + (size_t)(wn * 64 + nt * 16 + m) * K + quad * 8;

  f32x4 acc[4][4] = {};

#pragma unroll 2
  for (int k0 = 0; k0 < K; k0 += BK) {
    short8 bf[4], af[4];
#pragma unroll
    for (int nt = 0; nt < 4; ++nt) bf[nt] = *(const short8*)(pb[nt] + k0);
#pragma unroll
    for (int mt = 0; mt < 4; ++mt) af[mt] = *(const short8*)(pa[mt] + k0);
#pragma unroll
    for (int mt = 0; mt < 4; ++mt)
#pragma unroll
      for (int nt = 0; nt < 4; ++nt)
        acc[mt][nt] = __builtin_amdgcn_mfma_f32_16x16x32_bf16(
            af[mt], bf[nt], acc[mt][nt], 0, 0, 0);
  }

  float part[4][4];
#pragma unroll
  for (int mt = 0; mt < 4; ++mt)
#pragma unroll
    for (int r = 0; r < 4; ++r) part[mt][r] = 0.0f;
#pragma unroll
  for (int nt = 0; nt < 4; ++nt) {
    int col = wn * 64 + nt * 16 + m;
    float bb = cqh[col];
    float w2 = Wh2[col];
#pragma unroll
    for (int mt = 0; mt < 4; ++mt)
#pragma unroll
      for (int r = 0; r < 4; ++r)
        part[mt][r] += fmaxf(acc[mt][nt][r] + bb, 0.0f) * w2;
  }
#pragma unroll
  for (int off = 8; off > 0; off >>= 1)
#pragma unroll
    for (int mt = 0; mt < 4; ++mt)
#pragma unroll
      for (int r = 0; r < 4; ++r)
        part[mt][r] += __shfl_xor(part[mt][r], off, 64);
  if (m == 0) {
#pragma unroll
    for (int mt = 0; mt < 4; ++mt)
#pragma unroll
      for (int r = 0; r < 4; ++r)
        red[wm * 64 + mt * 16 + quad * 4 + r][wn] = part[mt][r];
  }
  __syncthreads();
  if (tid < 128) {
    int grow = row0 + tid;
    if (grow < M) out[grow] = red[tid][0] + red[tid][1] + bh2[0];
  }
}

// ---------------- aggregation: H[i] = relu(u_i + (y_i + sum_j y_j) / (deg+1))
__global__ __launch_bounds__(256) void aggregate(
    const u16* __restrict__ C, const int* __restrict__ row_ofs,
    const int* __restrict__ col_idx, u16* __restrict__ H, int Nn) {
  int node = blockIdx.x * 4 + (threadIdx.x >> 6);
  if (node >= Nn) return;
  int lane = threadIdx.x & 63;
  int s = row_ofs[node], e = row_ofs[node + 1];
  float inv = 1.0f / (float)(e - s + 1);
  const u16* crow = C + (size_t)node * 512;
  u16x4 y0 = *(const u16x4*)(crow + 256 + lane * 4);
  float a0 = bf2f(y0[0]), a1 = bf2f(y0[1]), a2 = bf2f(y0[2]), a3 = bf2f(y0[3]);
  int t = s;
  for (; t + 4 <= e; t += 4) {
    int j0 = col_idx[t], j1 = col_idx[t + 1], j2 = col_idx[t + 2], j3 = col_idx[t + 3];
    u16x4 v0 = *(const u16x4*)(C + (size_t)j0 * 512 + 256 + lane * 4);
    u16x4 v1 = *(const u16x4*)(C + (size_t)j1 * 512 + 256 + lane * 4);
    u16x4 v2 = *(const u16x4*)(C + (size_t)j2 * 512 + 256 + lane * 4);
    u16x4 v3 = *(const u16x4*)(C + (size_t)j3 * 512 + 256 + lane * 4);
    a0 += bf2f(v0[0]) + bf2f(v1[0]) + bf2f(v2[0]) + bf2f(v3[0]);
    a1 += bf2f(v0[1]) + bf2f(v1[1]) + bf2f(v2[1]) + bf2f(v3[1]);
    a2 += bf2f(v0[2]) + bf2f(v1[2]) + bf2f(v2[2]) + bf2f(v3[2]);
    a3 += bf2f(v0[3]) + bf2f(v1[3]) + bf2f(v2[3]) + bf2f(v3[3]);
  }
  for (; t < e; ++t) {
    int j = col_idx[t];
    u16x4 yj = *(const u16x4*)(C + (size_t)j * 512 + 256 + lane * 4);
    a0 += bf2f(yj[0]); a1 += bf2f(yj[1]); a2 += bf2f(yj[2]); a3 += bf2f(yj[3]);
  }
  u16x4 u = *(const u16x4*)(crow + lane * 4);
  u16x4 o;
  o[0] = f2bf(fmaxf(bf2f(u[0]) + a0 * inv, 0.0f));
  o[1] = f2bf(fmaxf(bf2f(u[1]) + a1 * inv, 0.0f));
  o[2] = f2bf(fmaxf(bf2f(u[2]) + a2 * inv, 0.0f));
  o[3] = f2bf(fmaxf(bf2f(u[3]) + a3 * inv, 0.0f));
  *(u16x4*)(H + (size_t)node * 256 + lane * 4) = o;
}

extern "C" void kernel_launch(void* const* d_in, const int* in_sizes, int n_in,
                              void* d_out, int out_size, void* d_ws, size_t ws_size,
                              hipStream_t stream) {
  const float* x   = (const float*)d_in[0];
  const int*   ei  = (const int*)d_in[1];
  const float* q   = (const float*)d_in[2];
  const float* W1  = (const float*)d_in[3];
  const float* b1  = (const float*)d_in[4];
  const float* W2  = (const float*)d_in[5];
  const float* b2  = (const float*)d_in[6];
  const float* Wh1 = (const float*)d_in[7];
  const float* bh1 = (const float*)d_in[8];
  const float* Wh2 = (const float*)d_in[9];
  const float* bh2 = (const float*)d_in[10];

  const int N = in_sizes[0] / 384;
  const int E = in_sizes[1] / 2;
  const int Npad = ((N + 127) / 128) * 128;
  const int* esrc = ei;
  const int* edst = ei + E;

  size_t off = 0;
  auto alloc = [&](size_t bytes) -> void* {
    void* p = (char*)d_ws + off;
    off += (bytes + 255) & ~(size_t)255;
    return p;
  };
  int* deg     = (int*)alloc((size_t)N * 4);
  int* row_ofs = (int*)alloc((size_t)(N + 1) * 4);
  int* cursor  = (int*)alloc((size_t)N * 4);
  int* colidx  = (int*)alloc((size_t)E * 4);
  int* pref    = (int*)alloc((size_t)N * 4);
  int* bsum    = (int*)alloc(256 * 4);
  u16* B1t = (u16*)alloc((size_t)512 * 384 * 2);
  u16* B2t = (u16*)alloc((size_t)512 * 256 * 2);
  u16* Bht = (u16*)alloc((size_t)128 * 256 * 2);
  float* cq1 = (float*)alloc(256 * 4);
  float* cq2 = (float*)alloc(256 * 4);
  float* cqh = (float*)alloc(128 * 4);
  u16* Cbuf = (u16*)alloc((size_t)Npad * 512 * 2);
  u16* Hbuf = (u16*)alloc((size_t)Npad * 256 * 2);

  (void)hipMemsetAsync(deg, 0, (size_t)N * 4, stream);
  int eb = (E + 255) / 256;
  int nb = (N + 255) / 256;
  build_deg<<<eb, 256, 0, stream>>>(edst, deg, E);
  scan1<<<nb, 256, 0, stream>>>(deg, pref, bsum, N);
  scan2<<<1, 256, 0, stream>>>(bsum, row_ofs, nb, N);
  scan3<<<nb, 256, 0, stream>>>(pref, bsum, row_ofs, cursor, N);
  csr_fill<<<eb, 256, 0, stream>>>(esrc, edst, cursor, colidx, E);

  pack_all<<<1664, 256, 0, stream>>>(W1, W2, Wh1, B1t, B2t, Bht);
  bias_all<<<640, 384, 0, stream>>>(W1, b1, W2, b2, Wh1, bh1, q, cq1, cq2, cqh);

  int gb64 = (N + 63) / 64;
  int mb = Npad / 128;
  int nb4 = (N + 3) / 4;
  // layer 1
  gemm_dir_f32a<<<gb64, 256, 0, stream>>>(x, B1t, Cbuf, cq1, N, 384, 256, 0);
  aggregate<<<nb4, 256, 0, stream>>>(Cbuf, row_ofs, colidx, Hbuf, N);
  // layer 2
  gemm_dir_bf16a<<<gb64, 256, 0, stream>>>(Hbuf, B2t, Cbuf, cq2, N, 256, 256, 0);
  aggregate<<<nb4, 256, 0, stream>>>(Cbuf, row_ofs, colidx, Hbuf, N);
  // fused head
  gemm_head<<<mb, 256, 0, stream>>>(Hbuf, Bht, cqh, Wh2, bh2, (float*)d_out, N, 256);
}

// Round 14
// 340.996 us; speedup vs baseline: 1.2743x; 1.2743x over previous
//
#include <hip/hip_runtime.h>
#include <cstdint>
#include <cstddef>

typedef unsigned short u16;
typedef short short8 __attribute__((ext_vector_type(8)));
typedef unsigned short u16x8 __attribute__((ext_vector_type(8)));
typedef unsigned short u16x4 __attribute__((ext_vector_type(4)));
typedef float f32x4 __attribute__((ext_vector_type(4)));

#define DEVI __device__ __forceinline__

#if defined(__has_builtin)
#if __has_builtin(__builtin_amdgcn_global_load_lds)
#define USE_GLD 1
#endif
#endif

DEVI float bf2f(u16 u) { return __uint_as_float(((unsigned)u) << 16); }
DEVI u16 f2bf(float f) {
  unsigned u = __float_as_uint(f);
  u += 0x7FFFu + ((u >> 16) & 1u);  // RNE
  return (u16)(u >> 16);
}

DEVI void stage16(const u16* __restrict__ g, u16* lds_base, int lane) {
#ifdef USE_GLD
  __builtin_amdgcn_global_load_lds(
      (const __attribute__((address_space(1))) unsigned int*)g,
      (__attribute__((address_space(3))) unsigned int*)lds_base, 16, 0, 0);
#else
  *(u16x8*)(lds_base + lane * 8) = *(const u16x8*)g;
#endif
}

// ---------------- CSR build ----------------
__global__ void build_deg(const int* __restrict__ dst, int* __restrict__ deg, int E) {
  int e = blockIdx.x * 256 + threadIdx.x;
  if (e < E) atomicAdd(&deg[dst[e]], 1);
}

__global__ __launch_bounds__(256) void scan1(const int* __restrict__ deg,
                                             int* __restrict__ pref,
                                             int* __restrict__ bsum, int Nn) {
  __shared__ int wsum[4];
  int i = blockIdx.x * 256 + threadIdx.x;
  int lane = threadIdx.x & 63, w = threadIdx.x >> 6;
  int v = (i < Nn) ? deg[i] : 0;
  int s = v;
  for (int off = 1; off < 64; off <<= 1) {
    int t = __shfl_up(s, off, 64);
    if (lane >= off) s += t;
  }
  if (lane == 63) wsum[w] = s;
  __syncthreads();
  int add = 0;
  for (int k = 0; k < w; ++k) add += wsum[k];
  int incl = s + add;
  if (i < Nn) pref[i] = incl - v;
  if (threadIdx.x == 255) bsum[blockIdx.x] = incl;
}

__global__ __launch_bounds__(256) void scan2(int* __restrict__ bsum,
                                             int* __restrict__ row_ofs,
                                             int nb, int Nn) {
  __shared__ int wsum[4];
  int t = threadIdx.x;
  int lane = t & 63, w = t >> 6;
  int v = (t < nb) ? bsum[t] : 0;
  int s = v;
  for (int off = 1; off < 64; off <<= 1) {
    int u = __shfl_up(s, off, 64);
    if (lane >= off) s += u;
  }
  if (lane == 63) wsum[w] = s;
  __syncthreads();
  int add = 0;
  for (int k = 0; k < w; ++k) add += wsum[k];
  int incl = s + add;
  if (t < nb) bsum[t] = incl - v;
  if (t == 255) row_ofs[Nn] = incl;
}

__global__ __launch_bounds__(256) void scan3(const int* __restrict__ pref,
                                             const int* __restrict__ bsum,
                                             int* __restrict__ row_ofs,
                                             int* __restrict__ cursor, int Nn) {
  int i = blockIdx.x * 256 + threadIdx.x;
  if (i < Nn) {
    int r = pref[i] + bsum[blockIdx.x];
    row_ofs[i] = r;
    cursor[i] = r;
  }
}

__global__ void csr_fill(const int* __restrict__ src, const int* __restrict__ dst,
                         int* __restrict__ cursor, int* __restrict__ col, int E) {
  int e = blockIdx.x * 256 + threadIdx.x;
  if (e < E) {
    int p = atomicAdd(&cursor[dst[e]], 1);
    col[p] = src[e];
  }
}

// ------------- merged weight pack -------------
__global__ __launch_bounds__(256) void pack_all(
    const float* __restrict__ W1, const float* __restrict__ W2,
    const float* __restrict__ Wh1, u16* __restrict__ B1t,
    u16* __restrict__ B2t, u16* __restrict__ Bht) {
  int b = blockIdx.x;
  if (b < 1024) {
    int c = b >> 1;
    int k = (b & 1) * 256 + threadIdx.x;
    if (k < 384) {
      float v = (c < 256) ? W1[(size_t)k * 256 + c]
                          : W1[(size_t)(384 + k) * 256 + (c - 256)];
      B1t[(size_t)c * 384 + k] = f2bf(v);
    }
  } else if (b < 1536) {
    int c = b - 1024;
    int k = threadIdx.x;
    float v = (c < 256) ? W2[(size_t)k * 256 + c]
                        : W2[(size_t)(256 + k) * 256 + (c - 256)];
    B2t[(size_t)c * 256 + k] = f2bf(v);
  } else {
    int c = b - 1536;
    int k = threadIdx.x;
    Bht[(size_t)c * 256 + k] = f2bf(Wh1[(size_t)k * 128 + c]);
  }
}

// ------------- merged bias -------------
__global__ __launch_bounds__(384) void bias_all(
    const float* __restrict__ W1, const float* __restrict__ b1,
    const float* __restrict__ W2, const float* __restrict__ b2,
    const float* __restrict__ Wh1, const float* __restrict__ bh1,
    const float* __restrict__ q, float* __restrict__ cq1,
    float* __restrict__ cq2, float* __restrict__ cqh) {
  __shared__ float part[6];
  int b = blockIdx.x;
  const float* W; const float* bb; float* o; int ld, roff, c;
  if (b < 256)      { W = W1;  bb = b1;  o = cq1; ld = 256; roff = 768; c = b; }
  else if (b < 512) { W = W2;  bb = b2;  o = cq2; ld = 256; roff = 512; c = b - 256; }
  else              { W = Wh1; bb = bh1; o = cqh; ld = 128; roff = 256; c = b - 512; }
  int t = threadIdx.x;
  float p = q[t] * W[(size_t)(roff + t) * ld + c];
  for (int off = 32; off > 0; off >>= 1) p += __shfl_down(p, off, 64);
  if ((t & 63) == 0) part[t >> 6] = p;
  __syncthreads();
  if (t == 0) {
    float acc = bb[c];
    for (int w = 0; w < 6; ++w) acc += part[w];
    o[c] = acc;
  }
}

// ================= wide GEMM (round-12 proven): 64 rows/block, Nc=512,
// 2 K-chunks per barrier pair; all tiles in ONE __shared__ array.
#define W_NC 512
#define ES 520
#define OFF_A0 0
#define OFF_A1 (64 * 32)
#define OFF_B0 (2 * 64 * 32)
#define OFF_B1 (2 * 64 * 32 + 512 * 32)
#define SMEM_TOT (2 * 64 * 32 + 2 * 512 * 32)

#define GEMM512_COMPUTE(LA, LB)                                                \
  {                                                                            \
    short8 bfr[8];                                                             \
    _Pragma("unroll") for (int nt = 0; nt < 8; ++nt) bfr[nt] =                 \
        *(const short8*)&(LB)[((wave * 128 + nt * 16 + m) * 4 + csel) * 8];    \
    _Pragma("unroll") for (int mt = 0; mt < 4; ++mt) {                         \
      short8 af = *(const short8*)&(LA)[((mt * 16 + m) * 4 + csel) * 8];       \
      _Pragma("unroll") for (int nt = 0; nt < 8; ++nt)                         \
          acc[mt][nt] = __builtin_amdgcn_mfma_f32_16x16x32_bf16(               \
              af, bfr[nt], acc[mt][nt], 0, 0, 0);                              \
    }                                                                          \
  }

#define GEMM512_EPILOGUE()                                                     \
  {                                                                            \
    u16* et = lds_b0;                                                          \
    _Pragma("unroll") for (int mt = 0; mt < 4; ++mt) {                         \
      __syncthreads();                                                         \
      _Pragma("unroll") for (int nt = 0; nt < 8; ++nt) {                       \
        int col = wave * 128 + nt * 16 + m;                                    \
        float bb = (col < bias_len) ? bias[col] : 0.0f;                        \
        _Pragma("unroll") for (int r = 0; r < 4; ++r) {                        \
          float v = acc[mt][nt][r] + bb;                                       \
          if (relu) v = fmaxf(v, 0.0f);                                        \
          et[(quad * 4 + r) * ES + col] = f2bf(v);                             \
        }                                                                      \
      }                                                                        \
      __syncthreads();                                                         \
      _Pragma("unroll") for (int p = 0; p < 4; ++p) {                          \
        int row_loc = p * 4 + wave;                                            \
        int grow = row0 + mt * 16 + row_loc;                                   \
        if (grow < M)                                                          \
          *(u16x8*)&C[(size_t)grow * W_NC + lane * 8] =                        \
              *(const u16x8*)&et[row_loc * ES + lane * 8];                     \
      }                                                                        \
    }                                                                          \
  }

#define GEMM512_B_SETUP()                                                      \
  const u16* pbB[8];                                                           \
  _Pragma("unroll") for (int p = 0; p < 8; ++p) {                              \
    int L = p * 256 + tid;                                                     \
    int c = L >> 2, qs = L & 3;                                                \
    int g = qs ^ ((c >> 1) & 3);                                               \
    pbB[p] = Bt + (size_t)c * K + g * 8;                                       \
  }

#define GEMM512_B_STAGE2()                                                     \
  _Pragma("unroll") for (int p = 0; p < 8; ++p) {                              \
    u16* d = lds_b0 + (size_t)(p * 256 + wave * 64) * 8;                       \
    stage16(pbB[p], d, lane);                                                  \
    stage16(pbB[p] + 32, d + (512 * 32), lane);                                \
    pbB[p] += 64;                                                              \
  }

__global__ __launch_bounds__(256, 2) void gemm512_f32a(
    const float* __restrict__ A, const u16* __restrict__ Bt,
    u16* __restrict__ C, const float* __restrict__ bias,
    int M, int K, int bias_len, int relu) {
  __shared__ __align__(16) u16 smem[SMEM_TOT];
  u16* lds_a0 = smem + OFF_A0;
  u16* lds_a1 = smem + OFF_A1;
  u16* lds_b0 = smem + OFF_B0;
  u16* lds_b1 = smem + OFF_B1;

  const int tid = threadIdx.x;
  const int lane = tid & 63;
  const int wave = tid >> 6;
  const int row0 = blockIdx.x * 64;
  const int m = lane & 15;
  const int quad = lane >> 4;
  const int csel = quad ^ ((m >> 1) & 3);

  const int rA = tid >> 2;
  const int qA = tid & 3;
  const int sA = rA * 4 + (qA ^ ((rA >> 1) & 3));
  int ga = row0 + rA; if (ga >= M) ga = M - 1;
  const float* pa = A + (size_t)ga * K + qA * 8;

  GEMM512_B_SETUP()

  f32x4 acc[4][8] = {};

  f32x4 v0a = *(const f32x4*)pa, v0b = *(const f32x4*)(pa + 4);
  f32x4 v1a = *(const f32x4*)(pa + 32), v1b = *(const f32x4*)(pa + 36);
  pa += 64;

  for (int k0 = 0; k0 < K; k0 += 64) {
    __syncthreads();
    GEMM512_B_STAGE2()
    u16x8 h0, h1;
#pragma unroll
    for (int j = 0; j < 4; ++j) {
      h0[j] = f2bf(v0a[j]); h0[j + 4] = f2bf(v0b[j]);
      h1[j] = f2bf(v1a[j]); h1[j + 4] = f2bf(v1b[j]);
    }
    *(u16x8*)&lds_a0[sA * 8] = h0;
    *(u16x8*)&lds_a1[sA * 8] = h1;
    const float* pn = (k0 + 64 < K) ? pa : A;
    f32x4 n0a = *(const f32x4*)pn, n0b = *(const f32x4*)(pn + 4);
    f32x4 n1a = *(const f32x4*)(pn + 32), n1b = *(const f32x4*)(pn + 36);
    pa += 64;
    __syncthreads();
    GEMM512_COMPUTE(lds_a0, lds_b0)
    GEMM512_COMPUTE(lds_a1, lds_b1)
    v0a = n0a; v0b = n0b; v1a = n1a; v1b = n1b;
  }

  GEMM512_EPILOGUE()
}

__global__ __launch_bounds__(256, 2) void gemm512_bf16a(
    const u16* __restrict__ A, const u16* __restrict__ Bt,
    u16* __restrict__ C, const float* __restrict__ bias,
    int M, int K, int bias_len, int relu) {
  __shared__ __align__(16) u16 smem[SMEM_TOT];
  u16* lds_a0 = smem + OFF_A0;
  u16* lds_a1 = smem + OFF_A1;
  u16* lds_b0 = smem + OFF_B0;
  u16* lds_b1 = smem + OFF_B1;

  const int tid = threadIdx.x;
  const int lane = tid & 63;
  const int wave = tid >> 6;
  const int row0 = blockIdx.x * 64;
  const int m = lane & 15;
  const int quad = lane >> 4;
  const int csel = quad ^ ((m >> 1) & 3);

  const int rA = tid >> 2;
  const int qA = tid & 3;
  const int sA = rA * 4 + (qA ^ ((rA >> 1) & 3));
  int ga = row0 + rA; if (ga >= M) ga = M - 1;
  const u16* pa = A + (size_t)ga * K + qA * 8;

  GEMM512_B_SETUP()

  f32x4 acc[4][8] = {};

  u16x8 va0 = *(const u16x8*)pa;
  u16x8 va1 = *(const u16x8*)(pa + 32);
  pa += 64;

  for (int k0 = 0; k0 < K; k0 += 64) {
    __syncthreads();
    GEMM512_B_STAGE2()
    *(u16x8*)&lds_a0[sA * 8] = va0;
    *(u16x8*)&lds_a1[sA * 8] = va1;
    const u16* pn = (k0 + 64 < K) ? pa : A;
    u16x8 na0 = *(const u16x8*)pn;
    u16x8 na1 = *(const u16x8*)(pn + 32);
    pa += 64;
    __syncthreads();
    GEMM512_COMPUTE(lds_a0, lds_b0)
    GEMM512_COMPUTE(lds_a1, lds_b1)
    va0 = na0; va1 = na1;
  }

  GEMM512_EPILOGUE()
}

// ========== fused head (round-12 proven): out = relu(h2@Wh1h+cqh).Wh2+bh2 ====
#define BM 128
#define BK 32

__global__ __launch_bounds__(256) void gemm_head(
    const u16* __restrict__ A, const u16* __restrict__ Bt,
    const float* __restrict__ cqh, const float* __restrict__ Wh2,
    const float* __restrict__ bh2, float* __restrict__ out, int M, int K) {
  __shared__ __align__(16) u16 lds_a[BM * BK];
  __shared__ __align__(16) u16 lds_b[BM * BK];
  __shared__ float red[128][2];

  const int tid = threadIdx.x;
  const int lane = tid & 63;
  const int wave = tid >> 6;
  const int wm = wave & 1, wn = wave >> 1;
  const int row0 = blockIdx.x * BM;
  const int m = lane & 15;
  const int quad = lane >> 4;
  const int csel = quad ^ ((m >> 1) & 3);

  const int r0 = tid >> 2, r1 = 64 + r0;
  const int cs = tid & 3;
  const int s0 = r0 * 4 + (cs ^ ((r0 >> 1) & 3));
  const int s1 = r1 * 4 + (cs ^ ((r1 >> 1) & 3));
  const int cb0 = cs ^ ((r0 >> 1) & 3);
  const int cb1 = cs ^ ((r1 >> 1) & 3);
  int ga0 = row0 + r0; if (ga0 >= M) ga0 = M - 1;
  int ga1 = row0 + r1; if (ga1 >= M) ga1 = M - 1;
  const u16* pa0 = A + (size_t)ga0 * K + cs * 8;
  const u16* pa1 = A + (size_t)ga1 * K + cs * 8;
  const u16* pb0 = Bt + (size_t)r0 * K + cb0 * 8;
  const u16* pb1 = Bt + (size_t)r1 * K + cb1 * 8;
  u16* lb0 = lds_b + (size_t)(wave * 64) * 8;
  u16* lb1 = lds_b + (size_t)(256 + wave * 64) * 8;

  f32x4 acc[4][4] = {};

  u16x8 va0 = *(const u16x8*)pa0; pa0 += BK;
  u16x8 va1 = *(const u16x8*)pa1; pa1 += BK;

  for (int k0 = 0; k0 < K; k0 += BK) {
    __syncthreads();
    stage16(pb0, lb0, lane); pb0 += BK;
    stage16(pb1, lb1, lane); pb1 += BK;
    *(u16x8*)&lds_a[s0 * 8] = va0;
    *(u16x8*)&lds_a[s1 * 8] = va1;
    const u16* n0 = (k0 + BK < K) ? pa0 : A;
    const u16* n1 = (k0 + BK < K) ? pa1 : A;
    u16x8 w0 = *(const u16x8*)n0;
    u16x8 w1 = *(const u16x8*)n1;
    pa0 += BK; pa1 += BK;
    __syncthreads();

    short8 af[4], bfv[4];
#pragma unroll
    for (int mt = 0; mt < 4; ++mt)
      af[mt] = *(const short8*)&lds_a[((wm * 64 + mt * 16 + m) * 4 + csel) * 8];
#pragma unroll
    for (int nt = 0; nt < 4; ++nt)
      bfv[nt] = *(const short8*)&lds_b[((wn * 64 + nt * 16 + m) * 4 + csel) * 8];
#pragma unroll
    for (int mt = 0; mt < 4; ++mt)
#pragma unroll
      for (int nt = 0; nt < 4; ++nt)
        acc[mt][nt] = __builtin_amdgcn_mfma_f32_16x16x32_bf16(
            af[mt], bfv[nt], acc[mt][nt], 0, 0, 0);
    va0 = w0; va1 = w1;
  }

  float part[4][4];
#pragma unroll
  for (int mt = 0; mt < 4; ++mt)
#pragma unroll
    for (int r = 0; r < 4; ++r) part[mt][r] = 0.0f;
#pragma unroll
  for (int nt = 0; nt < 4; ++nt) {
    int col = wn * 64 + nt * 16 + m;
    float bb = cqh[col];
    float w2 = Wh2[col];
#pragma unroll
    for (int mt = 0; mt < 4; ++mt)
#pragma unroll
      for (int r = 0; r < 4; ++r)
        part[mt][r] += fmaxf(acc[mt][nt][r] + bb, 0.0f) * w2;
  }
#pragma unroll
  for (int off = 8; off > 0; off >>= 1)
#pragma unroll
    for (int mt = 0; mt < 4; ++mt)
#pragma unroll
      for (int r = 0; r < 4; ++r)
        part[mt][r] += __shfl_xor(part[mt][r], off, 64);
  if (m == 0) {
#pragma unroll
    for (int mt = 0; mt < 4; ++mt)
#pragma unroll
      for (int r = 0; r < 4; ++r)
        red[wm * 64 + mt * 16 + quad * 4 + r][wn] = part[mt][r];
  }
  __syncthreads();
  if (tid < 128) {
    int grow = row0 + tid;
    if (grow < M) out[grow] = red[tid][0] + red[tid][1] + bh2[0];
  }
}

// ---------------- aggregation: H[i] = relu(u_i + (y_i + sum_j y_j)/(deg+1))
// 2 nodes per wave: 32 lanes x u16x8 (16B) per node-row. Each gather instr
// moves 1KB (2 full 512B rows). 4-deep unroll keeps serial depth ~2 at deg~8.
__global__ __launch_bounds__(256) void aggregate(
    const u16* __restrict__ C, const int* __restrict__ row_ofs,
    const int* __restrict__ col_idx, u16* __restrict__ H, int Nn) {
  int node = blockIdx.x * 8 + (threadIdx.x >> 5);
  if (node >= Nn) return;
  int l = threadIdx.x & 31;
  int s = row_ofs[node], e = row_ofs[node + 1];
  float inv = 1.0f / (float)(e - s + 1);
  const u16* crow = C + (size_t)node * 512;
  u16x8 y0 = *(const u16x8*)(crow + 256 + l * 8);
  float a[8];
#pragma unroll
  for (int j = 0; j < 8; ++j) a[j] = bf2f(y0[j]);
  int t = s;
  for (; t + 4 <= e; t += 4) {
    int j0 = col_idx[t], j1 = col_idx[t + 1], j2 = col_idx[t + 2], j3 = col_idx[t + 3];
    u16x8 v0 = *(const u16x8*)(C + (size_t)j0 * 512 + 256 + l * 8);
    u16x8 v1 = *(const u16x8*)(C + (size_t)j1 * 512 + 256 + l * 8);
    u16x8 v2 = *(const u16x8*)(C + (size_t)j2 * 512 + 256 + l * 8);
    u16x8 v3 = *(const u16x8*)(C + (size_t)j3 * 512 + 256 + l * 8);
#pragma unroll
    for (int j = 0; j < 8; ++j)
      a[j] += (bf2f(v0[j]) + bf2f(v1[j])) + (bf2f(v2[j]) + bf2f(v3[j]));
  }
  for (; t < e; ++t) {
    int jj = col_idx[t];
    u16x8 vj = *(const u16x8*)(C + (size_t)jj * 512 + 256 + l * 8);
#pragma unroll
    for (int j = 0; j < 8; ++j) a[j] += bf2f(vj[j]);
  }
  u16x8 u = *(const u16x8*)(crow + l * 8);
  u16x8 o;
#pragma unroll
  for (int j = 0; j < 8; ++j)
    o[j] = f2bf(fmaxf(bf2f(u[j]) + a[j] * inv, 0.0f));
  *(u16x8*)(H + (size_t)node * 256 + l * 8) = o;
}

extern "C" void kernel_launch(void* const* d_in, const int* in_sizes, int n_in,
                              void* d_out, int out_size, void* d_ws, size_t ws_size,
                              hipStream_t stream) {
  const float* x   = (const float*)d_in[0];
  const int*   ei  = (const int*)d_in[1];
  const float* q   = (const float*)d_in[2];
  const float* W1  = (const float*)d_in[3];
  const float* b1  = (const float*)d_in[4];
  const float* W2  = (const float*)d_in[5];
  const float* b2  = (const float*)d_in[6];
  const float* Wh1 = (const float*)d_in[7];
  const float* bh1 = (const float*)d_in[8];
  const float* Wh2 = (const float*)d_in[9];
  const float* bh2 = (const float*)d_in[10];

  const int N = in_sizes[0] / 384;
  const int E = in_sizes[1] / 2;
  const int Npad = ((N + 127) / 128) * 128;
  const int* esrc = ei;
  const int* edst = ei + E;

  size_t off = 0;
  auto alloc = [&](size_t bytes) -> void* {
    void* p = (char*)d_ws + off;
    off += (bytes + 255) & ~(size_t)255;
    return p;
  };
  int* deg     = (int*)alloc((size_t)N * 4);
  int* row_ofs = (int*)alloc((size_t)(N + 1) * 4);
  int* cursor  = (int*)alloc((size_t)N * 4);
  int* colidx  = (int*)alloc((size_t)E * 4);
  int* pref    = (int*)alloc((size_t)N * 4);
  int* bsum    = (int*)alloc(256 * 4);
  u16* B1t = (u16*)alloc((size_t)512 * 384 * 2);
  u16* B2t = (u16*)alloc((size_t)512 * 256 * 2);
  u16* Bht = (u16*)alloc((size_t)128 * 256 * 2);
  float* cq1 = (float*)alloc(256 * 4);
  float* cq2 = (float*)alloc(256 * 4);
  float* cqh = (float*)alloc(128 * 4);
  u16* Cbuf = (u16*)alloc((size_t)Npad * 512 * 2);
  u16* Hbuf = (u16*)alloc((size_t)Npad * 256 * 2);

  (void)hipMemsetAsync(deg, 0, (size_t)N * 4, stream);
  int eb = (E + 255) / 256;
  int nb = (N + 255) / 256;
  build_deg<<<eb, 256, 0, stream>>>(edst, deg, E);
  scan1<<<nb, 256, 0, stream>>>(deg, pref, bsum, N);
  scan2<<<1, 256, 0, stream>>>(bsum, row_ofs, nb, N);
  scan3<<<nb, 256, 0, stream>>>(pref, bsum, row_ofs, cursor, N);
  csr_fill<<<eb, 256, 0, stream>>>(esrc, edst, cursor, colidx, E);

  pack_all<<<1664, 256, 0, stream>>>(W1, W2, Wh1, B1t, B2t, Bht);
  bias_all<<<640, 384, 0, stream>>>(W1, b1, W2, b2, Wh1, bh1, q, cq1, cq2, cqh);

  int gb64 = (N + 63) / 64;
  int mb = Npad / 128;
  int nb8 = (N + 7) / 8;
  // layer 1
  gemm512_f32a<<<gb64, 256, 0, stream>>>(x, B1t, Cbuf, cq1, N, 384, 256, 0);
  aggregate<<<nb8, 256, 0, stream>>>(Cbuf, row_ofs, colidx, Hbuf, N);
  // layer 2
  gemm512_bf16a<<<gb64, 256, 0, stream>>>(Hbuf, B2t, Cbuf, cq2, N, 256, 256, 0);
  aggregate<<<nb8, 256, 0, stream>>>(Cbuf, row_ofs, colidx, Hbuf, N);
  // fused head
  gemm_head<<<mb, 256, 0, stream>>>(Hbuf, Bht, cqh, Wh2, bh2, (float*)d_out, N, 256);
}